// Round 6
// baseline (393.028 us; speedup 1.0000x reference)
//
#include <hip/hip_runtime.h>
#include <hip/hip_bf16.h>

typedef __attribute__((ext_vector_type(8))) short short8;
typedef __attribute__((ext_vector_type(4))) float f32x4;
typedef __attribute__((ext_vector_type(4))) unsigned short ushort4v;

static __device__ __forceinline__ unsigned short f2bf(float f) {
  unsigned u = __float_as_uint(f);
  unsigned r = (u + 0x7fffu + ((u >> 16) & 1u)) >> 16;
  return (unsigned short)r;
}
static __device__ __forceinline__ short8 pack8(float4 a, float4 b) {
  short8 r;
  r[0] = (short)f2bf(a.x); r[1] = (short)f2bf(a.y);
  r[2] = (short)f2bf(a.z); r[3] = (short)f2bf(a.w);
  r[4] = (short)f2bf(b.x); r[5] = (short)f2bf(b.y);
  r[6] = (short)f2bf(b.z); r[7] = (short)f2bf(b.w);
  return r;
}

// ---------------------------------------------------------------------------
// 128x128-tile GEMM: out[m][n] = (sum_k X[m][k]*W[n][k] + bias[n]) * scale
// X: [8192][768] fp32 (XF32=1) or bf16 (XF32=0); W: [768][768] fp32 [out,in];
// bias fp32. fp32->bf16 conversion happens in registers during LDS staging.
// OUTF32=1: out fp32 row-major [8192][768] (final d_out).
// OUTF32=0: vt_mode=0 -> bf16 row-major; vt_mode=1 -> bf16 V^T [b][h][d][s].
// ---------------------------------------------------------------------------
template<int XF32, int OUTF32>
__device__ __forceinline__ void gemm128(
    const void* Xp, const float* W, const float* bias,
    void* outp, float scale, int vt_mode, int bm, int bn)
{
  __shared__ unsigned short Als[128 * 32];
  __shared__ unsigned short Bls[128 * 32];

  const int tid = threadIdx.x;
  const int wave = tid >> 6, lane = tid & 63;
  const int g = lane >> 4, lo = lane & 15;
  const int wr = wave >> 1, wc = wave & 1;
  const int m0 = bm * 128, n0 = bn * 128;

  const f32x4 vzero = {0.f, 0.f, 0.f, 0.f};
  f32x4 acc[4][4];
#pragma unroll
  for (int m = 0; m < 4; ++m)
#pragma unroll
    for (int n = 0; n < 4; ++n) acc[m][n] = vzero;

  const int arow = tid >> 1;        // 0..127
  const int acol = (tid & 1) * 16;  // 0 or 16
  const float* Af = nullptr;
  const unsigned short* Ab = nullptr;
  if constexpr (XF32) Af = (const float*)Xp + (size_t)(m0 + arow) * 768 + acol;
  else                Ab = (const unsigned short*)Xp + (size_t)(m0 + arow) * 768 + acol;
  const float* Brow = W + (size_t)(n0 + arow) * 768 + acol;

  for (int k0 = 0; k0 < 768; k0 += 32) {
    short8 va0, va1;
    if constexpr (XF32) {
      float4 f0 = *(const float4*)(Af + k0);
      float4 f1 = *(const float4*)(Af + k0 + 4);
      float4 f2 = *(const float4*)(Af + k0 + 8);
      float4 f3 = *(const float4*)(Af + k0 + 12);
      va0 = pack8(f0, f1);
      va1 = pack8(f2, f3);
    } else {
      va0 = *(const short8*)(Ab + k0);
      va1 = *(const short8*)(Ab + k0 + 8);
    }
    float4 g0 = *(const float4*)(Brow + k0);
    float4 g1 = *(const float4*)(Brow + k0 + 4);
    float4 g2 = *(const float4*)(Brow + k0 + 8);
    float4 g3 = *(const float4*)(Brow + k0 + 12);
    short8 vb0 = pack8(g0, g1);
    short8 vb1 = pack8(g2, g3);

    __syncthreads();  // previous tile fully consumed
    *(short8*)(Als + arow * 32 + acol)     = va0;
    *(short8*)(Als + arow * 32 + acol + 8) = va1;
    *(short8*)(Bls + arow * 32 + acol)     = vb0;
    *(short8*)(Bls + arow * 32 + acol + 8) = vb1;
    __syncthreads();  // tile visible

    short8 af[4], bf[4];
#pragma unroll
    for (int m = 0; m < 4; ++m)
      af[m] = *(const short8*)(Als + (wr * 64 + m * 16 + lo) * 32 + g * 8);
#pragma unroll
    for (int n = 0; n < 4; ++n)
      bf[n] = *(const short8*)(Bls + (wc * 64 + n * 16 + lo) * 32 + g * 8);
#pragma unroll
    for (int m = 0; m < 4; ++m)
#pragma unroll
      for (int n = 0; n < 4; ++n)
        acc[m][n] = __builtin_amdgcn_mfma_f32_16x16x32_bf16(af[m], bf[n], acc[m][n], 0, 0, 0);
  }

#pragma unroll
  for (int n = 0; n < 4; ++n) {
    const int ncol = n0 + wc * 64 + n * 16 + lo;
    const float bb = bias[ncol];
#pragma unroll
    for (int m = 0; m < 4; ++m) {
      const int rowb = m0 + wr * 64 + m * 16 + g * 4;
      if constexpr (OUTF32) {
        float* out = (float*)outp;
#pragma unroll
        for (int r = 0; r < 4; ++r)
          out[(size_t)(rowb + r) * 768 + ncol] = (acc[m][n][r] + bb) * scale;
      } else {
        unsigned short* out = (unsigned short*)outp;
        if (!vt_mode) {
#pragma unroll
          for (int r = 0; r < 4; ++r)
            out[(size_t)(rowb + r) * 768 + ncol] = f2bf((acc[m][n][r] + bb) * scale);
        } else {
          const int b = rowb >> 12, s = rowb & 4095;
          const int hh = ncol >> 6, d = ncol & 63;
          ushort4v pk;
#pragma unroll
          for (int r = 0; r < 4; ++r) pk[r] = f2bf((acc[m][n][r] + bb) * scale);
          *(ushort4v*)(out + (((size_t)b * 12 + hh) * 64 + d) * 4096 + s) = pk;
        }
      }
    }
  }
}

__global__ __launch_bounds__(256, 2) void qkv_proj(
    const float* __restrict__ Qi, const float* __restrict__ Ki,
    const float* __restrict__ Vi,
    const float* __restrict__ Wq, const float* __restrict__ bq,
    const float* __restrict__ Wk, const float* __restrict__ bk,
    const float* __restrict__ Wv, const float* __restrict__ bv,
    unsigned short* __restrict__ qo, unsigned short* __restrict__ ko,
    unsigned short* __restrict__ vto)
{
  const int z = blockIdx.z;
  const float* X = (z == 0) ? Qi : (z == 1) ? Ki : Vi;
  const float* W = (z == 0) ? Wq : (z == 1) ? Wk : Wv;
  const float* bb = (z == 0) ? bq : (z == 1) ? bk : bv;
  unsigned short* out = (z == 0) ? qo : (z == 1) ? ko : vto;
  const float scale = (z == 0) ? 0.125f : 1.0f;  // fold 1/sqrt(dk) into q
  gemm128<1, 0>(X, W, bb, out, scale, (z == 2) ? 1 : 0, blockIdx.x, blockIdx.y);
}

__global__ __launch_bounds__(256, 2) void out_proj(
    const unsigned short* __restrict__ X, const float* __restrict__ W,
    const float* __restrict__ bias, float* __restrict__ out)
{
  gemm128<0, 1>(X, W, bias, out, 1.0f, 0, blockIdx.x, blockIdx.y);
}

// ---------------------------------------------------------------------------
// Flash attention: q [8192][768] (pre-scaled bf16), k [8192][768] bf16,
// vt [B][H][64][4096] bf16. O written IN-PLACE into ow (== qw): each block
// reads only its own rows x head-slice rectangle of qw at start and writes
// the same rectangle at the end. grid (S/128, B*H), 4 waves, 32 q-rows/wave;
// KV tiles of 64 in XOR-swizzled LDS (G4: 128B rows would be 16-way).
// ---------------------------------------------------------------------------
__global__ __launch_bounds__(256, 2) void attn_fwd(
    const unsigned short* qw, const unsigned short* __restrict__ kw,
    const unsigned short* __restrict__ vtw, unsigned short* ow)
{
  __shared__ unsigned short Kls[64 * 64];
  __shared__ unsigned short Vls[64 * 64];
  __shared__ unsigned short Pls[4 * 32 * 72];  // per-wave [32][72] padded

  const int tid = threadIdx.x, wave = tid >> 6, lane = tid & 63;
  const int g = lane >> 4, lo = lane & 15;
  const int bh = blockIdx.y, b = bh / 12, hh = bh % 12;
  const int q0 = blockIdx.x * 128 + wave * 32;

  // hoisted Q A-fragments: aq[m][s]: rows q0+m*16+lo, k-dims s*32+g*8..+7
  short8 aq[2][2];
#pragma unroll
  for (int m = 0; m < 2; ++m)
#pragma unroll
    for (int s = 0; s < 2; ++s)
      aq[m][s] = *(const short8*)(qw + (size_t)(b * 4096 + q0 + m * 16 + lo) * 768
                                  + hh * 64 + s * 32 + g * 8);

  const f32x4 vzero = {0.f, 0.f, 0.f, 0.f};
  float mx[2][4], lsum[2][4];
  f32x4 oacc[2][4];
#pragma unroll
  for (int m = 0; m < 2; ++m) {
#pragma unroll
    for (int r = 0; r < 4; ++r) { mx[m][r] = -1e30f; lsum[m][r] = 0.f; }
#pragma unroll
    for (int n = 0; n < 4; ++n) oacc[m][n] = vzero;
  }

  unsigned short* Pw = Pls + wave * (32 * 72);
  char* Kb = (char*)Kls;
  char* Vb = (char*)Vls;

  // staging: thread covers row srow (0..63), 2 x 16B chunks sc, sc+1
  const int srow = tid >> 2;
  const int sc = (tid & 3) * 2;
  const unsigned short* krow = kw + ((size_t)b * 4096 + srow) * 768 + hh * 64;
  const unsigned short* vrow = vtw + ((size_t)bh * 64 + srow) * 4096;
  const int swz = (srow & 7) << 4;

  for (int kv0 = 0; kv0 < 4096; kv0 += 64) {
    short8 kl0 = *(const short8*)(krow + (size_t)kv0 * 768 + sc * 8);
    short8 kl1 = *(const short8*)(krow + (size_t)kv0 * 768 + sc * 8 + 8);
    short8 vl0 = *(const short8*)(vrow + kv0 + sc * 8);
    short8 vl1 = *(const short8*)(vrow + kv0 + sc * 8 + 8);
    __syncthreads();  // everyone done reading previous tile (+ drains aq loads)
    *(short8*)(Kb + srow * 128 + ((sc * 16) ^ swz))       = kl0;
    *(short8*)(Kb + srow * 128 + (((sc + 1) * 16) ^ swz)) = kl1;
    *(short8*)(Vb + srow * 128 + ((sc * 16) ^ swz))       = vl0;
    *(short8*)(Vb + srow * 128 + (((sc + 1) * 16) ^ swz)) = vl1;
    __syncthreads();  // tile visible

    // ---- S = q @ k^T (q pre-scaled by 1/8) ----
    f32x4 sa[2][4];
    {
      short8 bkf[4][2];
#pragma unroll
      for (int n = 0; n < 4; ++n) {
        const int row = n * 16 + lo;
        const int rsw = (row & 7) << 4;
#pragma unroll
        for (int s = 0; s < 2; ++s)
          bkf[n][s] = *(const short8*)(Kb + row * 128 + ((s * 64 + g * 16) ^ rsw));
      }
#pragma unroll
      for (int m = 0; m < 2; ++m)
#pragma unroll
        for (int n = 0; n < 4; ++n) {
          f32x4 t = vzero;
          t = __builtin_amdgcn_mfma_f32_16x16x32_bf16(aq[m][0], bkf[n][0], t, 0, 0, 0);
          t = __builtin_amdgcn_mfma_f32_16x16x32_bf16(aq[m][1], bkf[n][1], t, 0, 0, 0);
          sa[m][n] = t;
        }
    }

    // ---- online softmax (row = m*16 + g*4 + r, cols = n*16 + lo) ----
#pragma unroll
    for (int m = 0; m < 2; ++m) {
#pragma unroll
      for (int r = 0; r < 4; ++r) {
        float pm = fmaxf(fmaxf(sa[m][0][r], sa[m][1][r]),
                         fmaxf(sa[m][2][r], sa[m][3][r]));
        pm = fmaxf(pm, __shfl_xor(pm, 1));
        pm = fmaxf(pm, __shfl_xor(pm, 2));
        pm = fmaxf(pm, __shfl_xor(pm, 4));
        pm = fmaxf(pm, __shfl_xor(pm, 8));
        const float nm = fmaxf(mx[m][r], pm);
        const float fr = __expf(mx[m][r] - nm);  // first iter: exp(-huge)=0
        mx[m][r] = nm;
        float rsum = 0.f;
#pragma unroll
        for (int n = 0; n < 4; ++n) {
          const float p = __expf(sa[m][n][r] - nm);
          sa[m][n][r] = p;
          rsum += p;
        }
        rsum += __shfl_xor(rsum, 1);
        rsum += __shfl_xor(rsum, 2);
        rsum += __shfl_xor(rsum, 4);
        rsum += __shfl_xor(rsum, 8);
        lsum[m][r] = lsum[m][r] * fr + rsum;
#pragma unroll
        for (int nd = 0; nd < 4; ++nd) oacc[m][nd][r] *= fr;
        const int qrow = m * 16 + g * 4 + r;
#pragma unroll
        for (int n = 0; n < 4; ++n)
          Pw[qrow * 72 + n * 16 + lo] = f2bf(sa[m][n][r]);
      }
    }

    // ---- O += P @ V ----
    {
      short8 ap[2][2], bvf[4][2];
#pragma unroll
      for (int m = 0; m < 2; ++m)
#pragma unroll
        for (int s = 0; s < 2; ++s)
          ap[m][s] = *(const short8*)((char*)Pw + (m * 16 + lo) * 144 + s * 64 + g * 16);
#pragma unroll
      for (int nd = 0; nd < 4; ++nd) {
        const int row = nd * 16 + lo;
        const int rsw = (row & 7) << 4;
#pragma unroll
        for (int s = 0; s < 2; ++s)
          bvf[nd][s] = *(const short8*)(Vb + row * 128 + ((s * 64 + g * 16) ^ rsw));
      }
#pragma unroll
      for (int m = 0; m < 2; ++m)
#pragma unroll
        for (int nd = 0; nd < 4; ++nd) {
          oacc[m][nd] = __builtin_amdgcn_mfma_f32_16x16x32_bf16(ap[m][0], bvf[nd][0], oacc[m][nd], 0, 0, 0);
          oacc[m][nd] = __builtin_amdgcn_mfma_f32_16x16x32_bf16(ap[m][1], bvf[nd][1], oacc[m][nd], 0, 0, 0);
        }
    }
  }

  // epilogue: normalize, store merged-head bf16 [8192][768] (in-place ok)
#pragma unroll
  for (int m = 0; m < 2; ++m) {
#pragma unroll
    for (int r = 0; r < 4; ++r) {
      const float inv = 1.f / lsum[m][r];
      const size_t rowoff = (size_t)(b * 4096 + q0 + m * 16 + g * 4 + r) * 768 + hh * 64;
#pragma unroll
      for (int nd = 0; nd < 4; ++nd)
        ow[rowoff + nd * 16 + lo] = f2bf(oacc[m][nd][r] * inv);
    }
  }
}

extern "C" void kernel_launch(void* const* d_in, const int* in_sizes, int n_in,
                              void* d_out, int out_size, void* d_ws, size_t ws_size,
                              hipStream_t stream) {
  (void)in_sizes; (void)n_in; (void)out_size; (void)ws_size;
  const float* Qi = (const float*)d_in[0];
  const float* Ki = (const float*)d_in[1];
  const float* Vi = (const float*)d_in[2];
  const float* Wq = (const float*)d_in[3];
  const float* bq = (const float*)d_in[4];
  const float* Wk = (const float*)d_in[5];
  const float* bk = (const float*)d_in[6];
  const float* Wv = (const float*)d_in[7];
  const float* bv = (const float*)d_in[8];
  const float* Wo = (const float*)d_in[9];
  const float* bo = (const float*)d_in[10];

  // ws: q bf16 + v^T bf16 (25.2 MB). k bf16 scratch lives in d_out's first
  // 12.6 MB of its 25.2 MB fp32 buffer — consumed by attn_fwd, then fully
  // overwritten by out_proj's fp32 output (stream-ordered). Attention output
  // reuses qw in place.
  unsigned short* ws = (unsigned short*)d_ws;
  const size_t NTOK = 8192u * 768u;  // 6291456
  unsigned short* qw  = ws;
  unsigned short* vtw = ws + NTOK;
  unsigned short* kwp = (unsigned short*)d_out;

  qkv_proj<<<dim3(64, 6, 3), 256, 0, stream>>>(Qi, Ki, Vi, Wq, bq, Wk, bk,
                                               Wv, bv, qw, kwp, vtw);
  attn_fwd<<<dim3(32, 24, 1), 256, 0, stream>>>(qw, kwp, vtw, qw);
  out_proj<<<dim3(64, 6, 1), 256, 0, stream>>>(qw, Wo, bo, (float*)d_out);
}

// Round 7
// 347.487 us; speedup vs baseline: 1.1311x; 1.1311x over previous
//
#include <hip/hip_runtime.h>
#include <hip/hip_bf16.h>

typedef __attribute__((ext_vector_type(8))) short short8;
typedef __attribute__((ext_vector_type(4))) float f32x4;
typedef __attribute__((ext_vector_type(4))) unsigned short ushort4v;

static __device__ __forceinline__ unsigned short f2bf(float f) {
  unsigned u = __float_as_uint(f);
  unsigned r = (u + 0x7fffu + ((u >> 16) & 1u)) >> 16;
  return (unsigned short)r;
}
static __device__ __forceinline__ short8 pack8(float4 a, float4 b) {
  short8 r;
  r[0] = (short)f2bf(a.x); r[1] = (short)f2bf(a.y);
  r[2] = (short)f2bf(a.z); r[3] = (short)f2bf(a.w);
  r[4] = (short)f2bf(b.x); r[5] = (short)f2bf(b.y);
  r[6] = (short)f2bf(b.z); r[7] = (short)f2bf(b.w);
  return r;
}

// ---------------------------------------------------------------------------
// 128x128-tile GEMM: out[m][n] = (sum_k X[m][k]*W[n][k] + bias[n]) * scale
// X: [8192][768] fp32 (XF32=1) or bf16 (XF32=0); W: [768][768] fp32 [out,in];
// bias fp32. fp32->bf16 conversion happens in registers during LDS staging.
// OUTF32=1: out fp32 row-major (final d_out).
// OUTF32=0: vt_mode=0 -> bf16 row-major; vt_mode=1 -> bf16 V^T [b][h][d][s].
// ---------------------------------------------------------------------------
template<int XF32, int OUTF32>
__device__ __forceinline__ void gemm128(
    const void* Xp, const float* W, const float* bias,
    void* outp, float scale, int vt_mode, int bm, int bn)
{
  __shared__ unsigned short Als[128 * 32];
  __shared__ unsigned short Bls[128 * 32];

  const int tid = threadIdx.x;
  const int wave = tid >> 6, lane = tid & 63;
  const int g = lane >> 4, lo = lane & 15;
  const int wr = wave >> 1, wc = wave & 1;
  const int m0 = bm * 128, n0 = bn * 128;

  const f32x4 vzero = {0.f, 0.f, 0.f, 0.f};
  f32x4 acc[4][4];
#pragma unroll
  for (int m = 0; m < 4; ++m)
#pragma unroll
    for (int n = 0; n < 4; ++n) acc[m][n] = vzero;

  const int arow = tid >> 1;        // 0..127
  const int acol = (tid & 1) * 16;  // 0 or 16
  const float* Af = nullptr;
  const unsigned short* Ab = nullptr;
  if constexpr (XF32) Af = (const float*)Xp + (size_t)(m0 + arow) * 768 + acol;
  else                Ab = (const unsigned short*)Xp + (size_t)(m0 + arow) * 768 + acol;
  const float* Brow = W + (size_t)(n0 + arow) * 768 + acol;

  for (int k0 = 0; k0 < 768; k0 += 32) {
    short8 va0, va1;
    if constexpr (XF32) {
      float4 f0 = *(const float4*)(Af + k0);
      float4 f1 = *(const float4*)(Af + k0 + 4);
      float4 f2 = *(const float4*)(Af + k0 + 8);
      float4 f3 = *(const float4*)(Af + k0 + 12);
      va0 = pack8(f0, f1);
      va1 = pack8(f2, f3);
    } else {
      va0 = *(const short8*)(Ab + k0);
      va1 = *(const short8*)(Ab + k0 + 8);
    }
    float4 g0 = *(const float4*)(Brow + k0);
    float4 g1 = *(const float4*)(Brow + k0 + 4);
    float4 g2 = *(const float4*)(Brow + k0 + 8);
    float4 g3 = *(const float4*)(Brow + k0 + 12);
    short8 vb0 = pack8(g0, g1);
    short8 vb1 = pack8(g2, g3);

    __syncthreads();  // previous tile fully consumed
    *(short8*)(Als + arow * 32 + acol)     = va0;
    *(short8*)(Als + arow * 32 + acol + 8) = va1;
    *(short8*)(Bls + arow * 32 + acol)     = vb0;
    *(short8*)(Bls + arow * 32 + acol + 8) = vb1;
    __syncthreads();  // tile visible

    short8 af[4], bf[4];
#pragma unroll
    for (int m = 0; m < 4; ++m)
      af[m] = *(const short8*)(Als + (wr * 64 + m * 16 + lo) * 32 + g * 8);
#pragma unroll
    for (int n = 0; n < 4; ++n)
      bf[n] = *(const short8*)(Bls + (wc * 64 + n * 16 + lo) * 32 + g * 8);
#pragma unroll
    for (int m = 0; m < 4; ++m)
#pragma unroll
      for (int n = 0; n < 4; ++n)
        acc[m][n] = __builtin_amdgcn_mfma_f32_16x16x32_bf16(af[m], bf[n], acc[m][n], 0, 0, 0);
  }

#pragma unroll
  for (int n = 0; n < 4; ++n) {
    const int ncol = n0 + wc * 64 + n * 16 + lo;
    const float bb = bias[ncol];
#pragma unroll
    for (int m = 0; m < 4; ++m) {
      const int rowb = m0 + wr * 64 + m * 16 + g * 4;
      if constexpr (OUTF32) {
        float* out = (float*)outp;
#pragma unroll
        for (int r = 0; r < 4; ++r)
          out[(size_t)(rowb + r) * 768 + ncol] = (acc[m][n][r] + bb) * scale;
      } else {
        unsigned short* out = (unsigned short*)outp;
        if (!vt_mode) {
#pragma unroll
          for (int r = 0; r < 4; ++r)
            out[(size_t)(rowb + r) * 768 + ncol] = f2bf((acc[m][n][r] + bb) * scale);
        } else {
          const int b = rowb >> 12, s = rowb & 4095;
          const int hh = ncol >> 6, d = ncol & 63;
          ushort4v pk;
#pragma unroll
          for (int r = 0; r < 4; ++r) pk[r] = f2bf((acc[m][n][r] + bb) * scale);
          *(ushort4v*)(out + (((size_t)b * 12 + hh) * 64 + d) * 4096 + s) = pk;
        }
      }
    }
  }
}

__global__ __launch_bounds__(256, 2) void qkv_proj(
    const float* __restrict__ Qi, const float* __restrict__ Ki,
    const float* __restrict__ Vi,
    const float* __restrict__ Wq, const float* __restrict__ bq,
    const float* __restrict__ Wk, const float* __restrict__ bk,
    const float* __restrict__ Wv, const float* __restrict__ bv,
    unsigned short* __restrict__ qo, unsigned short* __restrict__ ko,
    unsigned short* __restrict__ vto)
{
  const int z = blockIdx.z;
  const float* X = (z == 0) ? Qi : (z == 1) ? Ki : Vi;
  const float* W = (z == 0) ? Wq : (z == 1) ? Wk : Wv;
  const float* bb = (z == 0) ? bq : (z == 1) ? bk : bv;
  unsigned short* out = (z == 0) ? qo : (z == 1) ? ko : vto;
  // q gets 1/sqrt(dk) * log2(e) so softmax runs in exp2 domain
  const float scale = (z == 0) ? 0.18033688011f : 1.0f;
  gemm128<1, 0>(X, W, bb, out, scale, (z == 2) ? 1 : 0, blockIdx.x, blockIdx.y);
}

__global__ __launch_bounds__(256, 2) void out_proj(
    const unsigned short* __restrict__ X, const float* __restrict__ W,
    const float* __restrict__ bias, float* __restrict__ out)
{
  gemm128<0, 1>(X, W, bias, out, 1.0f, 0, blockIdx.x, blockIdx.y);
}

// ---------------------------------------------------------------------------
// Flash attention v2: q [8192][768] (pre-scaled by 0.125*log2e, bf16),
// k [8192][768] bf16, vt [B][H][64][4096] bf16. O in-place into qw.
// grid (32, 24), 512 thr (8 waves), 16 q-rows/wave. KV tiles of 64 in
// XOR-swizzled LDS. Row-sum via ones-MFMA (no sum shuffle chain);
// softmax in exp2 domain; defer-max rescale skip.
// ---------------------------------------------------------------------------
__global__ __launch_bounds__(512, 6) void attn_fwd(
    const unsigned short* qw, const unsigned short* __restrict__ kw,
    const unsigned short* __restrict__ vtw, unsigned short* ow)
{
  __shared__ unsigned short Kls[64 * 64];
  __shared__ unsigned short Vls[64 * 64];
  __shared__ unsigned short Pls[8 * 16 * 72];  // per-wave [16][72]

  const int tid = threadIdx.x, wave = tid >> 6, lane = tid & 63;
  const int g = lane >> 4, lo = lane & 15;
  const int bh = blockIdx.y, b = bh / 12, hh = bh % 12;
  const int q0 = blockIdx.x * 128 + wave * 16;

  // Q A-fragments: rows q0+lo, k-dims s*32+g*8..+7
  short8 aq[2];
#pragma unroll
  for (int s = 0; s < 2; ++s)
    aq[s] = *(const short8*)(qw + (size_t)(b * 4096 + q0 + lo) * 768
                             + hh * 64 + s * 32 + g * 8);

  const f32x4 vzero = {0.f, 0.f, 0.f, 0.f};
  float mx[4];
  f32x4 lacc = vzero;   // row-sum accumulator via ones-MFMA
  f32x4 oacc[4];
#pragma unroll
  for (int r = 0; r < 4; ++r) mx[r] = -1e30f;
#pragma unroll
  for (int n = 0; n < 4; ++n) oacc[n] = vzero;

  short8 bone;  // B-fragment of bf16 1.0 -> D[row][*] = row-sum of A
#pragma unroll
  for (int j = 0; j < 8; ++j) bone[j] = (short)0x3F80;

  unsigned short* Pw = Pls + wave * (16 * 72);
  char* Kb = (char*)Kls;
  char* Vb = (char*)Vls;

  // staging: 512 threads cover 64 rows x 8 x 16B chunks (1 chunk each)
  const int srow = tid >> 3;
  const int sc = tid & 7;
  const unsigned short* krow = kw + ((size_t)b * 4096 + srow) * 768 + hh * 64 + sc * 8;
  const unsigned short* vrow = vtw + ((size_t)bh * 64 + srow) * 4096 + sc * 8;
  const int sdst = srow * 128 + ((sc * 16) ^ ((srow & 7) << 4));

  for (int kv0 = 0; kv0 < 4096; kv0 += 64) {
    short8 kl = *(const short8*)(krow + (size_t)kv0 * 768);
    short8 vl = *(const short8*)(vrow + kv0);
    __syncthreads();  // everyone done reading previous tile (+ drains aq loads)
    *(short8*)(Kb + sdst) = kl;
    *(short8*)(Vb + sdst) = vl;
    __syncthreads();  // tile visible

    // ---- S = q @ k^T (exp2-domain scale folded into q) ----
    f32x4 sa[4];
#pragma unroll
    for (int n = 0; n < 4; ++n) {
      const int row = n * 16 + lo;
      const int rsw = (row & 7) << 4;
      short8 bk0 = *(const short8*)(Kb + row * 128 + ((g * 16) ^ rsw));
      short8 bk1 = *(const short8*)(Kb + row * 128 + ((64 + g * 16) ^ rsw));
      f32x4 t = vzero;
      t = __builtin_amdgcn_mfma_f32_16x16x32_bf16(aq[0], bk0, t, 0, 0, 0);
      t = __builtin_amdgcn_mfma_f32_16x16x32_bf16(aq[1], bk1, t, 0, 0, 0);
      sa[n] = t;
    }

    // ---- online softmax (row = g*4 + r, cols = n*16 + lo) ----
#pragma unroll
    for (int r = 0; r < 4; ++r) {
      float pm = fmaxf(fmaxf(sa[0][r], sa[1][r]), fmaxf(sa[2][r], sa[3][r]));
      pm = fmaxf(pm, __shfl_xor(pm, 1));
      pm = fmaxf(pm, __shfl_xor(pm, 2));
      pm = fmaxf(pm, __shfl_xor(pm, 4));
      pm = fmaxf(pm, __shfl_xor(pm, 8));
      if (pm > mx[r]) {  // defer-max: skip rescale when max unchanged
        const float fr = exp2f(mx[r] - pm);  // first tile: exp2(-huge)=0
        mx[r] = pm;
        lacc[r] *= fr;
#pragma unroll
        for (int nd = 0; nd < 4; ++nd) oacc[nd][r] *= fr;
      }
#pragma unroll
      for (int n = 0; n < 4; ++n)
        Pw[(g * 4 + r) * 72 + n * 16 + lo] = f2bf(exp2f(sa[n][r] - mx[r]));
    }

    // ---- O += P @ V ; l += P @ 1 ----
    short8 ap0 = *(const short8*)((char*)Pw + lo * 144 + g * 16);
    short8 ap1 = *(const short8*)((char*)Pw + lo * 144 + 64 + g * 16);
#pragma unroll
    for (int nd = 0; nd < 4; ++nd) {
      const int row = nd * 16 + lo;
      const int rsw = (row & 7) << 4;
      short8 bv0 = *(const short8*)(Vb + row * 128 + ((g * 16) ^ rsw));
      short8 bv1 = *(const short8*)(Vb + row * 128 + ((64 + g * 16) ^ rsw));
      oacc[nd] = __builtin_amdgcn_mfma_f32_16x16x32_bf16(ap0, bv0, oacc[nd], 0, 0, 0);
      oacc[nd] = __builtin_amdgcn_mfma_f32_16x16x32_bf16(ap1, bv1, oacc[nd], 0, 0, 0);
    }
    lacc = __builtin_amdgcn_mfma_f32_16x16x32_bf16(ap0, bone, lacc, 0, 0, 0);
    lacc = __builtin_amdgcn_mfma_f32_16x16x32_bf16(ap1, bone, lacc, 0, 0, 0);
  }

  // epilogue: normalize, store merged-head bf16 [8192][768] (in-place ok)
#pragma unroll
  for (int r = 0; r < 4; ++r) {
    const float inv = 1.f / lacc[r];
    const size_t rowoff = (size_t)(b * 4096 + q0 + g * 4 + r) * 768 + hh * 64;
#pragma unroll
    for (int nd = 0; nd < 4; ++nd)
      ow[rowoff + nd * 16 + lo] = f2bf(oacc[nd][r] * inv);
  }
}

extern "C" void kernel_launch(void* const* d_in, const int* in_sizes, int n_in,
                              void* d_out, int out_size, void* d_ws, size_t ws_size,
                              hipStream_t stream) {
  (void)in_sizes; (void)n_in; (void)out_size; (void)ws_size;
  const float* Qi = (const float*)d_in[0];
  const float* Ki = (const float*)d_in[1];
  const float* Vi = (const float*)d_in[2];
  const float* Wq = (const float*)d_in[3];
  const float* bq = (const float*)d_in[4];
  const float* Wk = (const float*)d_in[5];
  const float* bk = (const float*)d_in[6];
  const float* Wv = (const float*)d_in[7];
  const float* bv = (const float*)d_in[8];
  const float* Wo = (const float*)d_in[9];
  const float* bo = (const float*)d_in[10];

  // ws: q bf16 + v^T bf16 (25.2 MB). k bf16 scratch in d_out's first 12.6 MB
  // (overwritten by out_proj's fp32 output at the end, stream-ordered).
  // Attention output reuses qw in place.
  unsigned short* ws = (unsigned short*)d_ws;
  const size_t NTOK = 8192u * 768u;  // 6291456
  unsigned short* qw  = ws;
  unsigned short* vtw = ws + NTOK;
  unsigned short* kwp = (unsigned short*)d_out;

  qkv_proj<<<dim3(64, 6, 3), 256, 0, stream>>>(Qi, Ki, Vi, Wq, bq, Wk, bk,
                                               Wv, bv, qw, kwp, vtw);
  attn_fwd<<<dim3(32, 24, 1), 512, 0, stream>>>(qw, kwp, vtw, qw);
  out_proj<<<dim3(64, 6, 1), 256, 0, stream>>>(qw, Wo, bo, (float*)d_out);
}

// Round 8
// 297.612 us; speedup vs baseline: 1.3206x; 1.1676x over previous
//
#include <hip/hip_runtime.h>
#include <hip/hip_bf16.h>

typedef __attribute__((ext_vector_type(8))) short short8;
typedef __attribute__((ext_vector_type(4))) float f32x4;
typedef __attribute__((ext_vector_type(4))) unsigned short ushort4v;

static __device__ __forceinline__ unsigned short f2bf(float f) {
  unsigned u = __float_as_uint(f);
  unsigned r = (u + 0x7fffu + ((u >> 16) & 1u)) >> 16;
  return (unsigned short)r;
}
static __device__ __forceinline__ short8 pack8(float4 a, float4 b) {
  short8 r;
  r[0] = (short)f2bf(a.x); r[1] = (short)f2bf(a.y);
  r[2] = (short)f2bf(a.z); r[3] = (short)f2bf(a.w);
  r[4] = (short)f2bf(b.x); r[5] = (short)f2bf(b.y);
  r[6] = (short)f2bf(b.z); r[7] = (short)f2bf(b.w);
  return r;
}

// DPP-based max over each 16-lane group (all lanes receive the result).
// 0xB1 = quad_perm[1,0,3,2] (xor1), 0x4E = quad_perm[2,3,0,1] (xor2),
// 0x141 = row_half_mirror (fold 8s), 0x140 = row_mirror (fold 16s).
template <int CTRL>
static __device__ __forceinline__ float fmax_dpp(float x) {
  int t = __builtin_amdgcn_update_dpp(__float_as_int(x), __float_as_int(x),
                                      CTRL, 0xF, 0xF, true);
  return fmaxf(x, __int_as_float(t));
}
static __device__ __forceinline__ float max16_dpp(float x) {
  x = fmax_dpp<0xB1>(x);
  x = fmax_dpp<0x4E>(x);
  x = fmax_dpp<0x141>(x);
  x = fmax_dpp<0x140>(x);
  return x;
}

// ---------------------------------------------------------------------------
// 128x128-tile GEMM: out[m][n] = (sum_k X[m][k]*W[n][k] + bias[n]) * scale
// X: [8192][768] fp32 (XF32=1) or bf16 (XF32=0); W: [768][768] fp32 [out,in];
// bias fp32. fp32->bf16 conversion happens in registers during LDS staging.
// OUTF32=1: out fp32 row-major (final d_out).
// OUTF32=0: vt_mode=0 -> bf16 row-major; vt_mode=1 -> bf16 V^T [b][h][d][s].
// ---------------------------------------------------------------------------
template<int XF32, int OUTF32>
__device__ __forceinline__ void gemm128(
    const void* Xp, const float* W, const float* bias,
    void* outp, float scale, int vt_mode, int bm, int bn)
{
  __shared__ unsigned short Als[128 * 32];
  __shared__ unsigned short Bls[128 * 32];

  const int tid = threadIdx.x;
  const int wave = tid >> 6, lane = tid & 63;
  const int g = lane >> 4, lo = lane & 15;
  const int wr = wave >> 1, wc = wave & 1;
  const int m0 = bm * 128, n0 = bn * 128;

  const f32x4 vzero = {0.f, 0.f, 0.f, 0.f};
  f32x4 acc[4][4];
#pragma unroll
  for (int m = 0; m < 4; ++m)
#pragma unroll
    for (int n = 0; n < 4; ++n) acc[m][n] = vzero;

  const int arow = tid >> 1;        // 0..127
  const int acol = (tid & 1) * 16;  // 0 or 16
  const float* Af = nullptr;
  const unsigned short* Ab = nullptr;
  if constexpr (XF32) Af = (const float*)Xp + (size_t)(m0 + arow) * 768 + acol;
  else                Ab = (const unsigned short*)Xp + (size_t)(m0 + arow) * 768 + acol;
  const float* Brow = W + (size_t)(n0 + arow) * 768 + acol;

  for (int k0 = 0; k0 < 768; k0 += 32) {
    short8 va0, va1;
    if constexpr (XF32) {
      float4 f0 = *(const float4*)(Af + k0);
      float4 f1 = *(const float4*)(Af + k0 + 4);
      float4 f2 = *(const float4*)(Af + k0 + 8);
      float4 f3 = *(const float4*)(Af + k0 + 12);
      va0 = pack8(f0, f1);
      va1 = pack8(f2, f3);
    } else {
      va0 = *(const short8*)(Ab + k0);
      va1 = *(const short8*)(Ab + k0 + 8);
    }
    float4 g0 = *(const float4*)(Brow + k0);
    float4 g1 = *(const float4*)(Brow + k0 + 4);
    float4 g2 = *(const float4*)(Brow + k0 + 8);
    float4 g3 = *(const float4*)(Brow + k0 + 12);
    short8 vb0 = pack8(g0, g1);
    short8 vb1 = pack8(g2, g3);

    __syncthreads();  // previous tile fully consumed
    *(short8*)(Als + arow * 32 + acol)     = va0;
    *(short8*)(Als + arow * 32 + acol + 8) = va1;
    *(short8*)(Bls + arow * 32 + acol)     = vb0;
    *(short8*)(Bls + arow * 32 + acol + 8) = vb1;
    __syncthreads();  // tile visible

    short8 af[4], bf[4];
#pragma unroll
    for (int m = 0; m < 4; ++m)
      af[m] = *(const short8*)(Als + (wr * 64 + m * 16 + lo) * 32 + g * 8);
#pragma unroll
    for (int n = 0; n < 4; ++n)
      bf[n] = *(const short8*)(Bls + (wc * 64 + n * 16 + lo) * 32 + g * 8);
#pragma unroll
    for (int m = 0; m < 4; ++m)
#pragma unroll
      for (int n = 0; n < 4; ++n)
        acc[m][n] = __builtin_amdgcn_mfma_f32_16x16x32_bf16(af[m], bf[n], acc[m][n], 0, 0, 0);
  }

#pragma unroll
  for (int n = 0; n < 4; ++n) {
    const int ncol = n0 + wc * 64 + n * 16 + lo;
    const float bb = bias[ncol];
#pragma unroll
    for (int m = 0; m < 4; ++m) {
      const int rowb = m0 + wr * 64 + m * 16 + g * 4;
      if constexpr (OUTF32) {
        float* out = (float*)outp;
#pragma unroll
        for (int r = 0; r < 4; ++r)
          out[(size_t)(rowb + r) * 768 + ncol] = (acc[m][n][r] + bb) * scale;
      } else {
        unsigned short* out = (unsigned short*)outp;
        if (!vt_mode) {
#pragma unroll
          for (int r = 0; r < 4; ++r)
            out[(size_t)(rowb + r) * 768 + ncol] = f2bf((acc[m][n][r] + bb) * scale);
        } else {
          const int b = rowb >> 12, s = rowb & 4095;
          const int hh = ncol >> 6, d = ncol & 63;
          ushort4v pk;
#pragma unroll
          for (int r = 0; r < 4; ++r) pk[r] = f2bf((acc[m][n][r] + bb) * scale);
          *(ushort4v*)(out + (((size_t)b * 12 + hh) * 64 + d) * 4096 + s) = pk;
        }
      }
    }
  }
}

__global__ __launch_bounds__(256, 2) void qkv_proj(
    const float* __restrict__ Qi, const float* __restrict__ Ki,
    const float* __restrict__ Vi,
    const float* __restrict__ Wq, const float* __restrict__ bq,
    const float* __restrict__ Wk, const float* __restrict__ bk,
    const float* __restrict__ Wv, const float* __restrict__ bv,
    unsigned short* __restrict__ qo, unsigned short* __restrict__ ko,
    unsigned short* __restrict__ vto)
{
  const int z = blockIdx.z;
  const float* X = (z == 0) ? Qi : (z == 1) ? Ki : Vi;
  const float* W = (z == 0) ? Wq : (z == 1) ? Wk : Wv;
  const float* bb = (z == 0) ? bq : (z == 1) ? bk : bv;
  unsigned short* out = (z == 0) ? qo : (z == 1) ? ko : vto;
  // q gets 1/sqrt(dk) * log2(e) so softmax runs in exp2 domain
  const float scale = (z == 0) ? 0.18033688011f : 1.0f;
  gemm128<1, 0>(X, W, bb, out, scale, (z == 2) ? 1 : 0, blockIdx.x, blockIdx.y);
}

__global__ __launch_bounds__(256, 2) void out_proj(
    const unsigned short* __restrict__ X, const float* __restrict__ W,
    const float* __restrict__ bias, float* __restrict__ out)
{
  gemm128<0, 1>(X, W, bias, out, 1.0f, 0, blockIdx.x, blockIdx.y);
}

// ---------------------------------------------------------------------------
// Flash attention v3: q [8192][768] (pre-scaled by 0.125*log2e, bf16),
// k [8192][768] bf16, vt [B][H][64][4096] bf16. O in-place into qw.
// grid (32, 24), 512 thr (8 waves), 16 q-rows/wave.
// v3 changes: DPP max-reduce (no DS shuffles), raw v_exp_f32, defer-max
// THR=8, K/V prefetch one tile ahead with raw barriers (vmcnt never drained
// at barriers -> load latency hidden under compute).
// ---------------------------------------------------------------------------
__global__ __launch_bounds__(512, 6) void attn_fwd(
    const unsigned short* qw, const unsigned short* __restrict__ kw,
    const unsigned short* __restrict__ vtw, unsigned short* ow)
{
  __shared__ unsigned short Kls[64 * 64];
  __shared__ unsigned short Vls[64 * 64];
  __shared__ unsigned short Pls[8 * 16 * 72];  // per-wave [16][72]

  const int tid = threadIdx.x, wave = tid >> 6, lane = tid & 63;
  const int g = lane >> 4, lo = lane & 15;
  const int bh = blockIdx.y, b = bh / 12, hh = bh % 12;
  const int q0 = blockIdx.x * 128 + wave * 16;

  // Q A-fragments: rows q0+lo, k-dims s*32+g*8..+7
  short8 aq[2];
#pragma unroll
  for (int s = 0; s < 2; ++s)
    aq[s] = *(const short8*)(qw + (size_t)(b * 4096 + q0 + lo) * 768
                             + hh * 64 + s * 32 + g * 8);

  const f32x4 vzero = {0.f, 0.f, 0.f, 0.f};
  float mx[4];
  f32x4 lacc = vzero;   // row-sum accumulator via ones-MFMA
  f32x4 oacc[4];
#pragma unroll
  for (int r = 0; r < 4; ++r) mx[r] = -1e30f;
#pragma unroll
  for (int n = 0; n < 4; ++n) oacc[n] = vzero;

  short8 bone;  // B-fragment of bf16 1.0 -> D[row][*] = row-sum of A
#pragma unroll
  for (int j = 0; j < 8; ++j) bone[j] = (short)0x3F80;

  unsigned short* Pw = Pls + wave * (16 * 72);
  char* Kb = (char*)Kls;
  char* Vb = (char*)Vls;

  // staging: 512 threads cover 64 rows x 8 x 16B chunks (1 chunk each)
  const int srow = tid >> 3;
  const int sc = tid & 7;
  const unsigned short* krow = kw + ((size_t)b * 4096 + srow) * 768 + hh * 64 + sc * 8;
  const unsigned short* vrow = vtw + ((size_t)bh * 64 + srow) * 4096 + sc * 8;
  const int sdst = srow * 128 + ((sc * 16) ^ ((srow & 7) << 4));

  // prefetch tile 0
  short8 kl = *(const short8*)(krow);
  short8 vl = *(const short8*)(vrow);

  for (int kv0 = 0; kv0 < 4096; kv0 += 64) {
    // WAR: all waves done reading previous tile's LDS. Raw barrier: does NOT
    // drain vmcnt, so the prefetched loads stay in flight.
    asm volatile("s_waitcnt lgkmcnt(0)" ::: "memory");
    __builtin_amdgcn_s_barrier();
    *(short8*)(Kb + sdst) = kl;   // compiler inserts vmcnt wait (data dep)
    *(short8*)(Vb + sdst) = vl;
    if (kv0 + 64 < 4096) {        // prefetch next tile (in flight over compute)
      kl = *(const short8*)(krow + (size_t)(kv0 + 64) * 768);
      vl = *(const short8*)(vrow + (kv0 + 64));
    }
    asm volatile("s_waitcnt lgkmcnt(0)" ::: "memory");  // my writes visible
    __builtin_amdgcn_s_barrier();                       // all writes visible
    __builtin_amdgcn_sched_barrier(0);                  // pin: no hoist above

    // ---- S = q @ k^T (exp2-domain scale folded into q) ----
    f32x4 sa[4];
#pragma unroll
    for (int n = 0; n < 4; ++n) {
      const int row = n * 16 + lo;
      const int rsw = (row & 7) << 4;
      short8 bk0 = *(const short8*)(Kb + row * 128 + ((g * 16) ^ rsw));
      short8 bk1 = *(const short8*)(Kb + row * 128 + ((64 + g * 16) ^ rsw));
      f32x4 t = vzero;
      t = __builtin_amdgcn_mfma_f32_16x16x32_bf16(aq[0], bk0, t, 0, 0, 0);
      t = __builtin_amdgcn_mfma_f32_16x16x32_bf16(aq[1], bk1, t, 0, 0, 0);
      sa[n] = t;
    }

    // ---- online softmax (row = g*4 + r, cols = n*16 + lo) ----
#pragma unroll
    for (int r = 0; r < 4; ++r) {
      float pm = fmaxf(fmaxf(sa[0][r], sa[1][r]), fmaxf(sa[2][r], sa[3][r]));
      pm = max16_dpp(pm);
      if (pm > mx[r] + 8.f) {  // defer-max: rescale only on big max growth
        const float fr = __builtin_amdgcn_exp2f(mx[r] - pm);  // 1st tile: 0
        mx[r] = pm;
        lacc[r] *= fr;
#pragma unroll
        for (int nd = 0; nd < 4; ++nd) oacc[nd][r] *= fr;
      }
#pragma unroll
      for (int n = 0; n < 4; ++n)
        Pw[(g * 4 + r) * 72 + n * 16 + lo] =
            f2bf(__builtin_amdgcn_exp2f(sa[n][r] - mx[r]));
    }

    // ---- O += P @ V ; l += P @ 1 ----
    short8 ap0 = *(const short8*)((char*)Pw + lo * 144 + g * 16);
    short8 ap1 = *(const short8*)((char*)Pw + lo * 144 + 64 + g * 16);
#pragma unroll
    for (int nd = 0; nd < 4; ++nd) {
      const int row = nd * 16 + lo;
      const int rsw = (row & 7) << 4;
      short8 bv0 = *(const short8*)(Vb + row * 128 + ((g * 16) ^ rsw));
      short8 bv1 = *(const short8*)(Vb + row * 128 + ((64 + g * 16) ^ rsw));
      oacc[nd] = __builtin_amdgcn_mfma_f32_16x16x32_bf16(ap0, bv0, oacc[nd], 0, 0, 0);
      oacc[nd] = __builtin_amdgcn_mfma_f32_16x16x32_bf16(ap1, bv1, oacc[nd], 0, 0, 0);
    }
    lacc = __builtin_amdgcn_mfma_f32_16x16x32_bf16(ap0, bone, lacc, 0, 0, 0);
    lacc = __builtin_amdgcn_mfma_f32_16x16x32_bf16(ap1, bone, lacc, 0, 0, 0);
  }

  // epilogue: normalize, store merged-head bf16 [8192][768] (in-place ok)
#pragma unroll
  for (int r = 0; r < 4; ++r) {
    const float inv = 1.f / lacc[r];
    const size_t rowoff = (size_t)(b * 4096 + q0 + g * 4 + r) * 768 + hh * 64;
#pragma unroll
    for (int nd = 0; nd < 4; ++nd)
      ow[rowoff + nd * 16 + lo] = f2bf(oacc[nd][r] * inv);
  }
}

extern "C" void kernel_launch(void* const* d_in, const int* in_sizes, int n_in,
                              void* d_out, int out_size, void* d_ws, size_t ws_size,
                              hipStream_t stream) {
  (void)in_sizes; (void)n_in; (void)out_size; (void)ws_size;
  const float* Qi = (const float*)d_in[0];
  const float* Ki = (const float*)d_in[1];
  const float* Vi = (const float*)d_in[2];
  const float* Wq = (const float*)d_in[3];
  const float* bq = (const float*)d_in[4];
  const float* Wk = (const float*)d_in[5];
  const float* bk = (const float*)d_in[6];
  const float* Wv = (const float*)d_in[7];
  const float* bv = (const float*)d_in[8];
  const float* Wo = (const float*)d_in[9];
  const float* bo = (const float*)d_in[10];

  // ws: q bf16 + v^T bf16 (25.2 MB). k bf16 scratch in d_out's first 12.6 MB
  // (overwritten by out_proj's fp32 output at the end, stream-ordered).
  // Attention output reuses qw in place.
  unsigned short* ws = (unsigned short*)d_ws;
  const size_t NTOK = 8192u * 768u;  // 6291456
  unsigned short* qw  = ws;
  unsigned short* vtw = ws + NTOK;
  unsigned short* kwp = (unsigned short*)d_out;

  qkv_proj<<<dim3(64, 6, 3), 256, 0, stream>>>(Qi, Ki, Vi, Wq, bq, Wk, bk,
                                               Wv, bv, qw, kwp, vtw);
  attn_fwd<<<dim3(32, 24, 1), 512, 0, stream>>>(qw, kwp, vtw, qw);
  out_proj<<<dim3(64, 6, 1), 256, 0, stream>>>(qw, Wo, bo, (float*)d_out);
}

// Round 9
// 296.685 us; speedup vs baseline: 1.3247x; 1.0031x over previous
//
#include <hip/hip_runtime.h>
#include <hip/hip_bf16.h>

typedef __attribute__((ext_vector_type(8))) short short8;
typedef __attribute__((ext_vector_type(4))) float f32x4;
typedef __attribute__((ext_vector_type(4))) unsigned short ushort4v;

static __device__ __forceinline__ unsigned short f2bf(float f) {
  unsigned u = __float_as_uint(f);
  unsigned r = (u + 0x7fffu + ((u >> 16) & 1u)) >> 16;
  return (unsigned short)r;
}
static __device__ __forceinline__ short8 pack8(float4 a, float4 b) {
  short8 r;
  r[0] = (short)f2bf(a.x); r[1] = (short)f2bf(a.y);
  r[2] = (short)f2bf(a.z); r[3] = (short)f2bf(a.w);
  r[4] = (short)f2bf(b.x); r[5] = (short)f2bf(b.y);
  r[6] = (short)f2bf(b.z); r[7] = (short)f2bf(b.w);
  return r;
}

// DPP-based max over each 16-lane group (all lanes receive the result).
template <int CTRL>
static __device__ __forceinline__ float fmax_dpp(float x) {
  int t = __builtin_amdgcn_update_dpp(__float_as_int(x), __float_as_int(x),
                                      CTRL, 0xF, 0xF, true);
  return fmaxf(x, __int_as_float(t));
}
static __device__ __forceinline__ float max16_dpp(float x) {
  x = fmax_dpp<0xB1>(x);   // quad_perm xor1
  x = fmax_dpp<0x4E>(x);   // quad_perm xor2
  x = fmax_dpp<0x141>(x);  // row_half_mirror
  x = fmax_dpp<0x140>(x);  // row_mirror
  return x;
}

// ---------------------------------------------------------------------------
// 128x128-tile GEMM: out[m][n] = (sum_k X[m][k]*W[n][k] + bias[n]) * scale
// (unchanged from round 8)
// ---------------------------------------------------------------------------
template<int XF32, int OUTF32>
__device__ __forceinline__ void gemm128(
    const void* Xp, const float* W, const float* bias,
    void* outp, float scale, int vt_mode, int bm, int bn)
{
  __shared__ unsigned short Als[128 * 32];
  __shared__ unsigned short Bls[128 * 32];

  const int tid = threadIdx.x;
  const int wave = tid >> 6, lane = tid & 63;
  const int g = lane >> 4, lo = lane & 15;
  const int wr = wave >> 1, wc = wave & 1;
  const int m0 = bm * 128, n0 = bn * 128;

  const f32x4 vzero = {0.f, 0.f, 0.f, 0.f};
  f32x4 acc[4][4];
#pragma unroll
  for (int m = 0; m < 4; ++m)
#pragma unroll
    for (int n = 0; n < 4; ++n) acc[m][n] = vzero;

  const int arow = tid >> 1;
  const int acol = (tid & 1) * 16;
  const float* Af = nullptr;
  const unsigned short* Ab = nullptr;
  if constexpr (XF32) Af = (const float*)Xp + (size_t)(m0 + arow) * 768 + acol;
  else                Ab = (const unsigned short*)Xp + (size_t)(m0 + arow) * 768 + acol;
  const float* Brow = W + (size_t)(n0 + arow) * 768 + acol;

  for (int k0 = 0; k0 < 768; k0 += 32) {
    short8 va0, va1;
    if constexpr (XF32) {
      float4 f0 = *(const float4*)(Af + k0);
      float4 f1 = *(const float4*)(Af + k0 + 4);
      float4 f2 = *(const float4*)(Af + k0 + 8);
      float4 f3 = *(const float4*)(Af + k0 + 12);
      va0 = pack8(f0, f1);
      va1 = pack8(f2, f3);
    } else {
      va0 = *(const short8*)(Ab + k0);
      va1 = *(const short8*)(Ab + k0 + 8);
    }
    float4 g0 = *(const float4*)(Brow + k0);
    float4 g1 = *(const float4*)(Brow + k0 + 4);
    float4 g2 = *(const float4*)(Brow + k0 + 8);
    float4 g3 = *(const float4*)(Brow + k0 + 12);
    short8 vb0 = pack8(g0, g1);
    short8 vb1 = pack8(g2, g3);

    __syncthreads();
    *(short8*)(Als + arow * 32 + acol)     = va0;
    *(short8*)(Als + arow * 32 + acol + 8) = va1;
    *(short8*)(Bls + arow * 32 + acol)     = vb0;
    *(short8*)(Bls + arow * 32 + acol + 8) = vb1;
    __syncthreads();

    short8 af[4], bf[4];
#pragma unroll
    for (int m = 0; m < 4; ++m)
      af[m] = *(const short8*)(Als + (wr * 64 + m * 16 + lo) * 32 + g * 8);
#pragma unroll
    for (int n = 0; n < 4; ++n)
      bf[n] = *(const short8*)(Bls + (wc * 64 + n * 16 + lo) * 32 + g * 8);
#pragma unroll
    for (int m = 0; m < 4; ++m)
#pragma unroll
      for (int n = 0; n < 4; ++n)
        acc[m][n] = __builtin_amdgcn_mfma_f32_16x16x32_bf16(af[m], bf[n], acc[m][n], 0, 0, 0);
  }

#pragma unroll
  for (int n = 0; n < 4; ++n) {
    const int ncol = n0 + wc * 64 + n * 16 + lo;
    const float bb = bias[ncol];
#pragma unroll
    for (int m = 0; m < 4; ++m) {
      const int rowb = m0 + wr * 64 + m * 16 + g * 4;
      if constexpr (OUTF32) {
        float* out = (float*)outp;
#pragma unroll
        for (int r = 0; r < 4; ++r)
          out[(size_t)(rowb + r) * 768 + ncol] = (acc[m][n][r] + bb) * scale;
      } else {
        unsigned short* out = (unsigned short*)outp;
        if (!vt_mode) {
#pragma unroll
          for (int r = 0; r < 4; ++r)
            out[(size_t)(rowb + r) * 768 + ncol] = f2bf((acc[m][n][r] + bb) * scale);
        } else {
          const int b = rowb >> 12, s = rowb & 4095;
          const int hh = ncol >> 6, d = ncol & 63;
          ushort4v pk;
#pragma unroll
          for (int r = 0; r < 4; ++r) pk[r] = f2bf((acc[m][n][r] + bb) * scale);
          *(ushort4v*)(out + (((size_t)b * 12 + hh) * 64 + d) * 4096 + s) = pk;
        }
      }
    }
  }
}

__global__ __launch_bounds__(256, 2) void qkv_proj(
    const float* __restrict__ Qi, const float* __restrict__ Ki,
    const float* __restrict__ Vi,
    const float* __restrict__ Wq, const float* __restrict__ bq,
    const float* __restrict__ Wk, const float* __restrict__ bk,
    const float* __restrict__ Wv, const float* __restrict__ bv,
    unsigned short* __restrict__ qo, unsigned short* __restrict__ ko,
    unsigned short* __restrict__ vto)
{
  const int z = blockIdx.z;
  const float* X = (z == 0) ? Qi : (z == 1) ? Ki : Vi;
  const float* W = (z == 0) ? Wq : (z == 1) ? Wk : Wv;
  const float* bb = (z == 0) ? bq : (z == 1) ? bk : bv;
  unsigned short* out = (z == 0) ? qo : (z == 1) ? ko : vto;
  // q gets 1/sqrt(dk) * log2(e) so softmax runs in exp2 domain
  const float scale = (z == 0) ? 0.18033688011f : 1.0f;
  gemm128<1, 0>(X, W, bb, out, scale, (z == 2) ? 1 : 0, blockIdx.x, blockIdx.y);
}

__global__ __launch_bounds__(256, 2) void out_proj(
    const unsigned short* __restrict__ X, const float* __restrict__ W,
    const float* __restrict__ bias, float* __restrict__ out)
{
  gemm128<0, 1>(X, W, bias, out, 1.0f, 0, blockIdx.x, blockIdx.y);
}

// ---------------------------------------------------------------------------
// Flash attention v4: q [8192][768] (pre-scaled by 0.125*log2e, bf16),
// k [8192][768] bf16, vt [B][H][64][4096] bf16. O in-place into qw.
// grid (32, 24), 512 thr (8 waves), 16 q-rows/wave.
// v4: unified LDS + base-reg/imm-offset addressing (key: swizzle (row&7) ==
// (lo&7) for n*16-strided rows -> all K/V read addrs = 1 base + imm),
// zero-VALU P->bf16 via d16_hi truncation (bias cancels: l = ones-MFMA of
// same truncated P), launch_bounds(512,4) for VGPR hoisting headroom.
// ---------------------------------------------------------------------------
__global__ __launch_bounds__(512, 4) void attn_fwd(
    const unsigned short* qw, const unsigned short* __restrict__ kw,
    const unsigned short* __restrict__ vtw, unsigned short* ow)
{
  // [0,8192): K tile 64x64 bf16 (swizzled rows of 128B)
  // [8192,16384): V tile 64x64 bf16 (same layout)
  // [16384,34816): P, per-wave [16][72] u16 (144B rows)
  __shared__ char LDS[34816];

  const int tid = threadIdx.x, wave = tid >> 6, lane = tid & 63;
  const int g = lane >> 4, lo = lane & 15;
  const int bh = blockIdx.y, b = bh / 12, hh = bh % 12;
  const int q0 = blockIdx.x * 128 + wave * 16;

  // Q A-fragments: rows q0+lo, k-dims s*32+g*8..+7
  short8 aq[2];
#pragma unroll
  for (int s = 0; s < 2; ++s)
    aq[s] = *(const short8*)(qw + (size_t)(b * 4096 + q0 + lo) * 768
                             + hh * 64 + s * 32 + g * 8);

  const f32x4 vzero = {0.f, 0.f, 0.f, 0.f};
  float mx[4];
  f32x4 lacc = vzero;   // row-sum accumulator via ones-MFMA
  f32x4 oacc[4];
#pragma unroll
  for (int r = 0; r < 4; ++r) mx[r] = -1e30f;
#pragma unroll
  for (int n = 0; n < 4; ++n) oacc[n] = vzero;

  short8 bone;  // B-fragment of bf16 1.0
#pragma unroll
  for (int j = 0; j < 8; ++j) bone[j] = (short)0x3F80;

  // ---- per-lane base offsets (loop-invariant; all reads use +imm) ----
  // K/V fragment reads: row = n*16+lo  =>  row&7 == lo&7 (n-independent!)
  const int rsw = (lo & 7) << 4;
  const int rb0 = lo * 128 + ((g * 16) ^ rsw);
  const int rb1 = lo * 128 + ((64 + g * 16) ^ rsw);
  char* const Kr0 = LDS + rb0;                 // + n*2048
  char* const Kr1 = LDS + rb1;
  char* const Vr0 = LDS + 8192 + rb0;          // + nd*2048
  char* const Vr1 = LDS + 8192 + rb1;
  char* const Pwr = LDS + 16384 + wave * 2304 + (g * 4) * 144 + lo * 2;  // +r*144+n*32
  char* const Prd = LDS + 16384 + wave * 2304 + lo * 144 + g * 16;       // +{0,64}

  // staging: 512 threads cover 64 rows x 8 x 16B chunks (1 chunk each)
  const int srow = tid >> 3;
  const int sc = tid & 7;
  const unsigned short* krow = kw + ((size_t)b * 4096 + srow) * 768 + hh * 64 + sc * 8;
  const unsigned short* vrow = vtw + ((size_t)bh * 64 + srow) * 4096 + sc * 8;
  const int sdst = srow * 128 + ((sc * 16) ^ ((srow & 7) << 4));
  char* const Ksd = LDS + sdst;
  char* const Vsd = LDS + 8192 + sdst;

  // prefetch tile 0
  short8 kl = *(const short8*)(krow);
  short8 vl = *(const short8*)(vrow);

  for (int kv0 = 0; kv0 < 4096; kv0 += 64) {
    // WAR barrier (raw: vmcnt NOT drained; prefetched loads stay in flight)
    asm volatile("s_waitcnt lgkmcnt(0)" ::: "memory");
    __builtin_amdgcn_s_barrier();
    *(short8*)Ksd = kl;   // compiler inserts vmcnt wait (data dep)
    *(short8*)Vsd = vl;
    if (kv0 + 64 < 4096) {
      kl = *(const short8*)(krow + (size_t)(kv0 + 64) * 768);
      vl = *(const short8*)(vrow + (kv0 + 64));
    }
    asm volatile("s_waitcnt lgkmcnt(0)" ::: "memory");
    __builtin_amdgcn_s_barrier();
    __builtin_amdgcn_sched_barrier(0);

    // ---- S = q @ k^T ----
    f32x4 sa[4];
#pragma unroll
    for (int n = 0; n < 4; ++n) {
      short8 bk0 = *(const short8*)(Kr0 + n * 2048);
      short8 bk1 = *(const short8*)(Kr1 + n * 2048);
      f32x4 t = vzero;
      t = __builtin_amdgcn_mfma_f32_16x16x32_bf16(aq[0], bk0, t, 0, 0, 0);
      t = __builtin_amdgcn_mfma_f32_16x16x32_bf16(aq[1], bk1, t, 0, 0, 0);
      sa[n] = t;
    }

    // ---- online softmax (row = g*4 + r, cols = n*16 + lo) ----
#pragma unroll
    for (int r = 0; r < 4; ++r) {
      float pm = fmaxf(fmaxf(sa[0][r], sa[1][r]), fmaxf(sa[2][r], sa[3][r]));
      pm = max16_dpp(pm);
      if (pm > mx[r] + 8.f) {  // defer-max
        const float fr = __builtin_amdgcn_exp2f(mx[r] - pm);
        mx[r] = pm;
        lacc[r] *= fr;
#pragma unroll
        for (int nd = 0; nd < 4; ++nd) oacc[nd][r] *= fr;
      }
#pragma unroll
      for (int n = 0; n < 4; ++n) {
        const float pv = __builtin_amdgcn_exp2f(sa[n][r] - mx[r]);
        // truncating bf16 store: fuses to ds_write_b16_d16_hi (0 VALU rounding)
        *(unsigned short*)(Pwr + r * 144 + n * 32) =
            (unsigned short)(__float_as_uint(pv) >> 16);
      }
    }

    // ---- O += P @ V ; l += P @ 1 ----
    short8 ap0 = *(const short8*)(Prd);
    short8 ap1 = *(const short8*)(Prd + 64);
#pragma unroll
    for (int nd = 0; nd < 4; ++nd) {
      short8 bv0 = *(const short8*)(Vr0 + nd * 2048);
      short8 bv1 = *(const short8*)(Vr1 + nd * 2048);
      oacc[nd] = __builtin_amdgcn_mfma_f32_16x16x32_bf16(ap0, bv0, oacc[nd], 0, 0, 0);
      oacc[nd] = __builtin_amdgcn_mfma_f32_16x16x32_bf16(ap1, bv1, oacc[nd], 0, 0, 0);
    }
    lacc = __builtin_amdgcn_mfma_f32_16x16x32_bf16(ap0, bone, lacc, 0, 0, 0);
    lacc = __builtin_amdgcn_mfma_f32_16x16x32_bf16(ap1, bone, lacc, 0, 0, 0);
  }

  // epilogue: normalize (RNE), store merged-head bf16 [8192][768]
#pragma unroll
  for (int r = 0; r < 4; ++r) {
    const float inv = 1.f / lacc[r];
    const size_t rowoff = (size_t)(b * 4096 + q0 + g * 4 + r) * 768 + hh * 64;
#pragma unroll
    for (int nd = 0; nd < 4; ++nd)
      ow[rowoff + nd * 16 + lo] = f2bf(oacc[nd][r] * inv);
  }
}

extern "C" void kernel_launch(void* const* d_in, const int* in_sizes, int n_in,
                              void* d_out, int out_size, void* d_ws, size_t ws_size,
                              hipStream_t stream) {
  (void)in_sizes; (void)n_in; (void)out_size; (void)ws_size;
  const float* Qi = (const float*)d_in[0];
  const float* Ki = (const float*)d_in[1];
  const float* Vi = (const float*)d_in[2];
  const float* Wq = (const float*)d_in[3];
  const float* bq = (const float*)d_in[4];
  const float* Wk = (const float*)d_in[5];
  const float* bk = (const float*)d_in[6];
  const float* Wv = (const float*)d_in[7];
  const float* bv = (const float*)d_in[8];
  const float* Wo = (const float*)d_in[9];
  const float* bo = (const float*)d_in[10];

  // ws: q bf16 + v^T bf16 (25.2 MB). k bf16 scratch in d_out's first 12.6 MB
  // (overwritten by out_proj's fp32 output at the end, stream-ordered).
  // Attention output reuses qw in place.
  unsigned short* ws = (unsigned short*)d_ws;
  const size_t NTOK = 8192u * 768u;  // 6291456
  unsigned short* qw  = ws;
  unsigned short* vtw = ws + NTOK;
  unsigned short* kwp = (unsigned short*)d_out;

  qkv_proj<<<dim3(64, 6, 3), 256, 0, stream>>>(Qi, Ki, Vi, Wq, bq, Wk, bk,
                                               Wv, bv, qw, kwp, vtw);
  attn_fwd<<<dim3(32, 24, 1), 512, 0, stream>>>(qw, kwp, vtw, qw);
  out_proj<<<dim3(64, 6, 1), 256, 0, stream>>>(qw, Wo, bo, (float*)d_out);
}

// Round 10
// 294.602 us; speedup vs baseline: 1.3341x; 1.0071x over previous
//
#include <hip/hip_runtime.h>
#include <hip/hip_bf16.h>

typedef __attribute__((ext_vector_type(8))) short short8;
typedef __attribute__((ext_vector_type(4))) float f32x4;
typedef __attribute__((ext_vector_type(4))) unsigned short ushort4v;

static __device__ __forceinline__ unsigned short f2bf(float f) {
  unsigned u = __float_as_uint(f);
  unsigned r = (u + 0x7fffu + ((u >> 16) & 1u)) >> 16;
  return (unsigned short)r;
}
static __device__ __forceinline__ short8 pack8(float4 a, float4 b) {
  short8 r;
  r[0] = (short)f2bf(a.x); r[1] = (short)f2bf(a.y);
  r[2] = (short)f2bf(a.z); r[3] = (short)f2bf(a.w);
  r[4] = (short)f2bf(b.x); r[5] = (short)f2bf(b.y);
  r[6] = (short)f2bf(b.z); r[7] = (short)f2bf(b.w);
  return r;
}

// DPP-based max over each 16-lane group (all lanes receive the result).
template <int CTRL>
static __device__ __forceinline__ float fmax_dpp(float x) {
  int t = __builtin_amdgcn_update_dpp(__float_as_int(x), __float_as_int(x),
                                      CTRL, 0xF, 0xF, true);
  return fmaxf(x, __int_as_float(t));
}
static __device__ __forceinline__ float max16_dpp(float x) {
  x = fmax_dpp<0xB1>(x);   // quad_perm xor1
  x = fmax_dpp<0x4E>(x);   // quad_perm xor2
  x = fmax_dpp<0x141>(x);  // row_half_mirror
  x = fmax_dpp<0x140>(x);  // row_mirror
  return x;
}

// ---------------------------------------------------------------------------
// 128x128-tile GEMM (unchanged)
// ---------------------------------------------------------------------------
template<int XF32, int OUTF32>
__device__ __forceinline__ void gemm128(
    const void* Xp, const float* W, const float* bias,
    void* outp, float scale, int vt_mode, int bm, int bn)
{
  __shared__ unsigned short Als[128 * 32];
  __shared__ unsigned short Bls[128 * 32];

  const int tid = threadIdx.x;
  const int wave = tid >> 6, lane = tid & 63;
  const int g = lane >> 4, lo = lane & 15;
  const int wr = wave >> 1, wc = wave & 1;
  const int m0 = bm * 128, n0 = bn * 128;

  const f32x4 vzero = {0.f, 0.f, 0.f, 0.f};
  f32x4 acc[4][4];
#pragma unroll
  for (int m = 0; m < 4; ++m)
#pragma unroll
    for (int n = 0; n < 4; ++n) acc[m][n] = vzero;

  const int arow = tid >> 1;
  const int acol = (tid & 1) * 16;
  const float* Af = nullptr;
  const unsigned short* Ab = nullptr;
  if constexpr (XF32) Af = (const float*)Xp + (size_t)(m0 + arow) * 768 + acol;
  else                Ab = (const unsigned short*)Xp + (size_t)(m0 + arow) * 768 + acol;
  const float* Brow = W + (size_t)(n0 + arow) * 768 + acol;

  for (int k0 = 0; k0 < 768; k0 += 32) {
    short8 va0, va1;
    if constexpr (XF32) {
      float4 f0 = *(const float4*)(Af + k0);
      float4 f1 = *(const float4*)(Af + k0 + 4);
      float4 f2 = *(const float4*)(Af + k0 + 8);
      float4 f3 = *(const float4*)(Af + k0 + 12);
      va0 = pack8(f0, f1);
      va1 = pack8(f2, f3);
    } else {
      va0 = *(const short8*)(Ab + k0);
      va1 = *(const short8*)(Ab + k0 + 8);
    }
    float4 g0 = *(const float4*)(Brow + k0);
    float4 g1 = *(const float4*)(Brow + k0 + 4);
    float4 g2 = *(const float4*)(Brow + k0 + 8);
    float4 g3 = *(const float4*)(Brow + k0 + 12);
    short8 vb0 = pack8(g0, g1);
    short8 vb1 = pack8(g2, g3);

    __syncthreads();
    *(short8*)(Als + arow * 32 + acol)     = va0;
    *(short8*)(Als + arow * 32 + acol + 8) = va1;
    *(short8*)(Bls + arow * 32 + acol)     = vb0;
    *(short8*)(Bls + arow * 32 + acol + 8) = vb1;
    __syncthreads();

    short8 af[4], bf[4];
#pragma unroll
    for (int m = 0; m < 4; ++m)
      af[m] = *(const short8*)(Als + (wr * 64 + m * 16 + lo) * 32 + g * 8);
#pragma unroll
    for (int n = 0; n < 4; ++n)
      bf[n] = *(const short8*)(Bls + (wc * 64 + n * 16 + lo) * 32 + g * 8);
#pragma unroll
    for (int m = 0; m < 4; ++m)
#pragma unroll
      for (int n = 0; n < 4; ++n)
        acc[m][n] = __builtin_amdgcn_mfma_f32_16x16x32_bf16(af[m], bf[n], acc[m][n], 0, 0, 0);
  }

#pragma unroll
  for (int n = 0; n < 4; ++n) {
    const int ncol = n0 + wc * 64 + n * 16 + lo;
    const float bb = bias[ncol];
#pragma unroll
    for (int m = 0; m < 4; ++m) {
      const int rowb = m0 + wr * 64 + m * 16 + g * 4;
      if constexpr (OUTF32) {
        float* out = (float*)outp;
#pragma unroll
        for (int r = 0; r < 4; ++r)
          out[(size_t)(rowb + r) * 768 + ncol] = (acc[m][n][r] + bb) * scale;
      } else {
        unsigned short* out = (unsigned short*)outp;
        if (!vt_mode) {
#pragma unroll
          for (int r = 0; r < 4; ++r)
            out[(size_t)(rowb + r) * 768 + ncol] = f2bf((acc[m][n][r] + bb) * scale);
        } else {
          const int b = rowb >> 12, s = rowb & 4095;
          const int hh = ncol >> 6, d = ncol & 63;
          ushort4v pk;
#pragma unroll
          for (int r = 0; r < 4; ++r) pk[r] = f2bf((acc[m][n][r] + bb) * scale);
          *(ushort4v*)(out + (((size_t)b * 12 + hh) * 64 + d) * 4096 + s) = pk;
        }
      }
    }
  }
}

__global__ __launch_bounds__(256, 2) void qkv_proj(
    const float* __restrict__ Qi, const float* __restrict__ Ki,
    const float* __restrict__ Vi,
    const float* __restrict__ Wq, const float* __restrict__ bq,
    const float* __restrict__ Wk, const float* __restrict__ bk,
    const float* __restrict__ Wv, const float* __restrict__ bv,
    unsigned short* __restrict__ qo, unsigned short* __restrict__ ko,
    unsigned short* __restrict__ vto)
{
  const int z = blockIdx.z;
  const float* X = (z == 0) ? Qi : (z == 1) ? Ki : Vi;
  const float* W = (z == 0) ? Wq : (z == 1) ? Wk : Wv;
  const float* bb = (z == 0) ? bq : (z == 1) ? bk : bv;
  unsigned short* out = (z == 0) ? qo : (z == 1) ? ko : vto;
  // q gets 1/sqrt(dk) * log2(e) so softmax runs in exp2 domain
  const float scale = (z == 0) ? 0.18033688011f : 1.0f;
  gemm128<1, 0>(X, W, bb, out, scale, (z == 2) ? 1 : 0, blockIdx.x, blockIdx.y);
}

__global__ __launch_bounds__(256, 2) void out_proj(
    const unsigned short* __restrict__ X, const float* __restrict__ W,
    const float* __restrict__ bias, float* __restrict__ out)
{
  gemm128<0, 1>(X, W, bias, out, 1.0f, 0, blockIdx.x, blockIdx.y);
}

// ---------------------------------------------------------------------------
// Flash attention v5: double-buffered K/V -> ONE barrier per KV-tile.
// Waves de-phase within the full-iteration window so MFMA (QK/PV) of one
// wave overlaps softmax VALU of another (m114). Loop unrolled x2 so the
// LDS buffer offset is a compile-time immediate.
// LDS map: K[2][64][128B swz] @0, V[2] @16384, P per-wave [16][72] @32768.
// ---------------------------------------------------------------------------
#define ATTN_TILE(BO, KWR, VWR, KLD, VLD, TNEXT)                               \
  {                                                                            \
    asm volatile("s_waitcnt lgkmcnt(0)" ::: "memory");                         \
    __builtin_amdgcn_s_barrier();                                              \
    __builtin_amdgcn_sched_barrier(0);                                         \
    /* ---- S = q @ k^T ---- */                                                \
    f32x4 sa[4];                                                               \
    _Pragma("unroll")                                                          \
    for (int n = 0; n < 4; ++n) {                                              \
      short8 bk0 = *(const short8*)(Kr0 + (BO) + n * 2048);                    \
      short8 bk1 = *(const short8*)(Kr1 + (BO) + n * 2048);                    \
      f32x4 t = vzero;                                                         \
      t = __builtin_amdgcn_mfma_f32_16x16x32_bf16(aq[0], bk0, t, 0, 0, 0);     \
      t = __builtin_amdgcn_mfma_f32_16x16x32_bf16(aq[1], bk1, t, 0, 0, 0);     \
      sa[n] = t;                                                               \
    }                                                                          \
    /* ---- stage next tile into other buffer + issue prefetch ---- */         \
    *(short8*)(Ksd + ((BO) ^ 8192)) = KWR;                                     \
    *(short8*)(Vsd + ((BO) ^ 8192)) = VWR;                                     \
    {                                                                          \
      int tp = (TNEXT);                                                        \
      if (tp > 63) tp = 63;                                                    \
      KLD = *(const short8*)(krow + (size_t)(tp * 64) * 768);                  \
      VLD = *(const short8*)(vrow + tp * 64);                                  \
    }                                                                          \
    /* ---- online softmax ---- */                                             \
    _Pragma("unroll")                                                          \
    for (int r = 0; r < 4; ++r) {                                              \
      float pm = fmaxf(fmaxf(sa[0][r], sa[1][r]), fmaxf(sa[2][r], sa[3][r]));  \
      pm = max16_dpp(pm);                                                      \
      if (pm > mx[r] + 8.f) {                                                  \
        const float fr = __builtin_amdgcn_exp2f(mx[r] - pm);                   \
        mx[r] = pm;                                                            \
        lacc[r] *= fr;                                                         \
        _Pragma("unroll")                                                      \
        for (int nd = 0; nd < 4; ++nd) oacc[nd][r] *= fr;                      \
      }                                                                        \
      _Pragma("unroll")                                                        \
      for (int n = 0; n < 4; ++n) {                                            \
        const float pv = __builtin_amdgcn_exp2f(sa[n][r] - mx[r]);             \
        *(unsigned short*)(Pwr + r * 144 + n * 32) =                           \
            (unsigned short)(__float_as_uint(pv) >> 16);                       \
      }                                                                        \
    }                                                                          \
    /* ---- O += P @ V ; l += P @ 1 ---- */                                    \
    short8 ap0 = *(const short8*)(Prd);                                        \
    short8 ap1 = *(const short8*)(Prd + 64);                                   \
    _Pragma("unroll")                                                          \
    for (int nd = 0; nd < 4; ++nd) {                                           \
      short8 bv0 = *(const short8*)(Vr0 + (BO) + nd * 2048);                   \
      short8 bv1 = *(const short8*)(Vr1 + (BO) + nd * 2048);                   \
      oacc[nd] = __builtin_amdgcn_mfma_f32_16x16x32_bf16(ap0, bv0, oacc[nd], 0, 0, 0); \
      oacc[nd] = __builtin_amdgcn_mfma_f32_16x16x32_bf16(ap1, bv1, oacc[nd], 0, 0, 0); \
    }                                                                          \
    lacc = __builtin_amdgcn_mfma_f32_16x16x32_bf16(ap0, bone, lacc, 0, 0, 0);  \
    lacc = __builtin_amdgcn_mfma_f32_16x16x32_bf16(ap1, bone, lacc, 0, 0, 0);  \
  }

__global__ __launch_bounds__(512, 4) void attn_fwd(
    const unsigned short* qw, const unsigned short* __restrict__ kw,
    const unsigned short* __restrict__ vtw, unsigned short* ow)
{
  __shared__ char LDS[51200];

  const int tid = threadIdx.x, wave = tid >> 6, lane = tid & 63;
  const int g = lane >> 4, lo = lane & 15;
  const int bh = blockIdx.y, b = bh / 12, hh = bh % 12;
  const int q0 = blockIdx.x * 128 + wave * 16;

  // Q A-fragments: rows q0+lo, k-dims s*32+g*8..+7
  short8 aq[2];
#pragma unroll
  for (int s = 0; s < 2; ++s)
    aq[s] = *(const short8*)(qw + (size_t)(b * 4096 + q0 + lo) * 768
                             + hh * 64 + s * 32 + g * 8);

  const f32x4 vzero = {0.f, 0.f, 0.f, 0.f};
  float mx[4];
  f32x4 lacc = vzero;
  f32x4 oacc[4];
#pragma unroll
  for (int r = 0; r < 4; ++r) mx[r] = -1e30f;
#pragma unroll
  for (int n = 0; n < 4; ++n) oacc[n] = vzero;

  short8 bone;  // bf16 1.0 B-fragment (row-sum via MFMA)
#pragma unroll
  for (int j = 0; j < 8; ++j) bone[j] = (short)0x3F80;

  // per-lane base offsets; all loop accesses are base + compile-time imm
  const int rsw = (lo & 7) << 4;
  const int rb0 = lo * 128 + ((g * 16) ^ rsw);
  const int rb1 = lo * 128 + ((64 + g * 16) ^ rsw);
  char* const Kr0 = LDS + rb0;                  // + BO + n*2048
  char* const Kr1 = LDS + rb1;
  char* const Vr0 = LDS + 16384 + rb0;          // + BO + nd*2048
  char* const Vr1 = LDS + 16384 + rb1;
  char* const Pwr = LDS + 32768 + wave * 2304 + (g * 4) * 144 + lo * 2;
  char* const Prd = LDS + 32768 + wave * 2304 + lo * 144 + g * 16;

  // staging: 512 threads cover 64 rows x 8 x 16B chunks
  const int srow = tid >> 3;
  const int sc = tid & 7;
  const unsigned short* krow = kw + ((size_t)b * 4096 + srow) * 768 + hh * 64 + sc * 8;
  const unsigned short* vrow = vtw + ((size_t)bh * 64 + srow) * 4096 + sc * 8;
  const int sdst = srow * 128 + ((sc * 16) ^ ((srow & 7) << 4));
  char* const Ksd = LDS + sdst;
  char* const Vsd = LDS + 16384 + sdst;

  // tile 0 -> buf0 (made visible by the first in-loop barrier)
  {
    short8 k0 = *(const short8*)(krow);
    short8 v0 = *(const short8*)(vrow);
    *(short8*)Ksd = k0;
    *(short8*)Vsd = v0;
  }
  // prefetch tile 1 into regs
  short8 klA = *(const short8*)(krow + (size_t)64 * 768);
  short8 vlA = *(const short8*)(vrow + 64);
  short8 klB, vlB;

  for (int t = 0; t < 64; t += 2) {
    ATTN_TILE(0,    klA, vlA, klB, vlB, t + 2)   // compute buf0 (tile t)
    ATTN_TILE(8192, klB, vlB, klA, vlA, t + 3)   // compute buf1 (tile t+1)
  }

  // epilogue: normalize (RNE), store merged-head bf16 [8192][768] (in-place)
#pragma unroll
  for (int r = 0; r < 4; ++r) {
    const float inv = 1.f / lacc[r];
    const size_t rowoff = (size_t)(b * 4096 + q0 + g * 4 + r) * 768 + hh * 64;
#pragma unroll
    for (int nd = 0; nd < 4; ++nd)
      ow[rowoff + nd * 16 + lo] = f2bf(oacc[nd][r] * inv);
  }
}

extern "C" void kernel_launch(void* const* d_in, const int* in_sizes, int n_in,
                              void* d_out, int out_size, void* d_ws, size_t ws_size,
                              hipStream_t stream) {
  (void)in_sizes; (void)n_in; (void)out_size; (void)ws_size;
  const float* Qi = (const float*)d_in[0];
  const float* Ki = (const float*)d_in[1];
  const float* Vi = (const float*)d_in[2];
  const float* Wq = (const float*)d_in[3];
  const float* bq = (const float*)d_in[4];
  const float* Wk = (const float*)d_in[5];
  const float* bk = (const float*)d_in[6];
  const float* Wv = (const float*)d_in[7];
  const float* bv = (const float*)d_in[8];
  const float* Wo = (const float*)d_in[9];
  const float* bo = (const float*)d_in[10];

  // ws: q bf16 + v^T bf16 (25.2 MB). k bf16 scratch in d_out's first 12.6 MB
  // (overwritten by out_proj's fp32 output at the end, stream-ordered).
  // Attention output reuses qw in place.
  unsigned short* ws = (unsigned short*)d_ws;
  const size_t NTOK = 8192u * 768u;  // 6291456
  unsigned short* qw  = ws;
  unsigned short* vtw = ws + NTOK;
  unsigned short* kwp = (unsigned short*)d_out;

  qkv_proj<<<dim3(64, 6, 3), 256, 0, stream>>>(Qi, Ki, Vi, Wq, bq, Wk, bk,
                                               Wv, bv, qw, kwp, vtw);
  attn_fwd<<<dim3(32, 24, 1), 512, 0, stream>>>(qw, kwp, vtw, qw);
  out_proj<<<dim3(64, 6, 1), 256, 0, stream>>>(qw, Wo, bo, (float*)d_out);
}